// Round 11
// baseline (273.891 us; speedup 1.0000x reference)
//
#include <hip/hip_runtime.h>
#include <hip/hip_bf16.h>

typedef __attribute__((ext_vector_type(4))) float f32x4;
typedef __attribute__((ext_vector_type(8))) short s16x8;
typedef __attribute__((ext_vector_type(8))) unsigned short u16x8;
typedef __attribute__((ext_vector_type(4))) unsigned short u16x4;

__device__ __forceinline__ unsigned short bfbits(float f) {
  unsigned int u = __builtin_bit_cast(unsigned int, f);
  return (unsigned short)((u + 0x8000u) >> 16);   // round-half-up to bf16
}

__device__ __forceinline__ void gll16(void* lds, const void* g) {
  __builtin_amdgcn_global_load_lds(
      (const __attribute__((address_space(1))) unsigned int*)g,
      (__attribute__((address_space(3))) unsigned int*)lds, 16, 0, 0);
}

// ---------------------------------------------------------------------------
// Merged prep: blocks [0,1824) transpose input, blocks [1824,2400) tile weights.
// Input: [32,56,56,256] f32 -> bf16 [b][h57][par][cq32][wp29][8]
//   element strides: wp:8 cq:232 par:7424 h:14848 b:846336
// Weights: [3,3,256,512] f32 -> bf16, K-step t=kpos*8+c/32, nb: [cq][nl][ce]
//   Wt index = (t*4+nb)*4096 + cq*1024 + nl*8 + ce
// ---------------------------------------------------------------------------
__global__ __launch_bounds__(256)
void prep_all(const float* __restrict__ in, __hip_bfloat16* __restrict__ dst,
              const float* __restrict__ w, __hip_bfloat16* __restrict__ wt) {
  int t = threadIdx.x;
  if (blockIdx.x < 1824) {
    __shared__ __align__(16) unsigned short row[14848];
    int bh = blockIdx.x;            // 32*57
    int h = bh % 57, b = bh / 57;
    __hip_bfloat16* d = (__hip_bfloat16*)dst + (long)bh * 14848;
    if (h < 56) {
      if (t < 64) {   // zero the wp=28 pad slots
        int par = t >> 5, cq = t & 31;
        u16x4 z = {0, 0, 0, 0};
        *(u16x4*)(row + (par * 32 + cq) * 232 + 224) = z;
        *(u16x4*)(row + (par * 32 + cq) * 232 + 228) = z;
      }
      const float* src = in + (long)(b * 56 + h) * 56 * 256;
#pragma unroll
      for (int j = 0; j < 14; ++j) {
        int idx = j * 256 + t;       // f32x4 index in row, 3584 total
        f32x4 v = *(const f32x4*)(src + idx * 4);
        int e0 = idx * 4;
        int ww = e0 >> 8, c = e0 & 255;
        int off = ((ww & 1) * 32 + (c >> 3)) * 232 + (ww >> 1) * 8 + (c & 7);
        u16x4 q = {bfbits(v[0]), bfbits(v[1]), bfbits(v[2]), bfbits(v[3])};
        *(u16x4*)(row + off) = q;
      }
      __syncthreads();
      for (int i = t; i < 1856; i += 256)
        *(u16x8*)(d + i * 8) = *(const u16x8*)(row + i * 8);
    } else {
      u16x8 z = {0, 0, 0, 0, 0, 0, 0, 0};
      for (int i = t; i < 1856; i += 256) *(u16x8*)(d + i * 8) = z;
    }
  } else {
    int u = (blockIdx.x - 1824) * 256 + t;   // 147456 threads
    int n = u & 511;
    int c8 = (u >> 9) & 31;
    int kpos = u >> 14;
    int tt = kpos * 8 + (c8 >> 2);
    int cq = c8 & 3;
    const float* src = w + ((kpos * 256 + c8 * 8) * 512) + n;
    u16x8 d;
#pragma unroll
    for (int j = 0; j < 8; ++j) d[j] = bfbits(src[j * 512]);
    int nb = n >> 7, nl = n & 127;
    *reinterpret_cast<u16x8*>(wt + ((tt * 4 + nb) * 4096 + cq * 1024 + nl * 8)) = d;
  }
}

// ---------------------------------------------------------------------------
// Main: implicit-GEMM conv, BM=128 BN=128 BK=32, 256 threads (4 waves,
// wave tile 64x64). 2 LDS buffers x (A 8KB + B 8KB) = 32KB -> 5 blocks/CU
// = 20 waves/CU (the occupancy lever). Stage(t+1) issued at TOP of step t
// (latency hides under the step's own ds_read+MFMA + cross-block TLP),
// vmcnt(0) drain at bottom, one raw barrier per K-step.
// ---------------------------------------------------------------------------
__global__ __launch_bounds__(256, 5)
void caps_main_fast(const __hip_bfloat16* __restrict__ inp,   // transposed bf16
                    const __hip_bfloat16* __restrict__ wt,
                    const float* __restrict__ bias1,
                    const float* __restrict__ capsW,
                    const float* __restrict__ capsB,
                    float* __restrict__ out) {
  __shared__ __align__(16) unsigned char smem[32768];   // 2 x (A 8KB + B 8KB)
  __hip_bfloat16* smem_e = (__hip_bfloat16*)smem;

  int bid = (int)blockIdx.x;
  bid = (bid & 7) * 98 + (bid >> 3);   // XCD swizzle (784 = 8*98, bijective)
  int mblk = bid >> 2;                 // 0..195
  int nb = bid & 3;
  int p0 = mblk * 128;

  int tid = threadIdx.x;
  int lane = tid & 63;
  int wv = tid >> 6;                   // 0..3
  int wm = (wv >> 1) * 64;
  int wn = (wv & 1) * 64;
  int col = lane & 15;
  int lq = lane >> 4;

  // A staging: wave wv stages cq=wv; lanes = pixels (16B stride, coalesced)
  int px0 = p0 + lane;
  int px1 = p0 + 64 + lane;
  int b0 = px0 / 784, r0 = px0 - b0 * 784;
  int h0 = r0 / 28, w0 = r0 - h0 * 28;
  int baseA0 = b0 * 846336 + 2 * h0 * 14848 + w0 * 8;
  int b1 = px1 / 784, r1 = px1 - b1 * 784;
  int h1 = r1 / 28, w1 = r1 - h1 * 28;
  int baseA1 = b1 * 846336 + 2 * h1 * 14848 + w1 * 8;

  const __hip_bfloat16* wtb = wt + nb * 4096;

  f32x4 acc[4][4] = {};

  auto stage = [&](int buf, int t) {
    int kp = t >> 3, tc = t & 7;
    int kh = (kp * 11) >> 5;           // kp/3 for 0..8
    int kw = kp - kh * 3;
    int koff = kh * 14848 + (kw & 1) * 7424 + (kw >> 1) * 8 + (tc * 4 + wv) * 232;
    __hip_bfloat16* sa = smem_e + buf * 8192;
    // A tile [cq][128][8]: wave wv covers cq=wv
    gll16(sa + wv * 1024, inp + baseA0 + koff);
    gll16(sa + wv * 1024 + 512, inp + baseA1 + koff);
    // B tile [cq][128][8]: wave wv covers cq=wv
    __hip_bfloat16* sb = sa + 4096;
    const __hip_bfloat16* bs = wtb + t * 16384 + wv * 1024 + lane * 8;
    gll16(sb + wv * 1024, bs);
    gll16(sb + wv * 1024 + 512, bs + 512);
  };

  // prologue
  stage(0, 0);
  __asm__ volatile("s_waitcnt vmcnt(0)" ::: "memory");
  __builtin_amdgcn_s_barrier();
  __asm__ volatile("" ::: "memory");

  for (int t = 0; t < 72; ++t) {
    int buf = t & 1;
    // prefetch t+1 into the other buffer (safe: prior barrier guarantees
    // no wave still reads buf^1; gll writes can't land before it either)
    if (t + 1 < 72) stage(buf ^ 1, t + 1);
    const __hip_bfloat16* sa = smem_e + buf * 8192;
    const __hip_bfloat16* sb = sa + 4096;
    s16x8 af[4], bq[4];
#pragma unroll
    for (int mf = 0; mf < 4; ++mf)
      af[mf] = *(const s16x8*)(sa + lq * 1024 + (wm + 16 * mf + col) * 8);
#pragma unroll
    for (int nf = 0; nf < 4; ++nf)
      bq[nf] = *(const s16x8*)(sb + lq * 1024 + (wn + 16 * nf + col) * 8);
    __builtin_amdgcn_s_setprio(1);
#pragma unroll
    for (int mf = 0; mf < 4; ++mf)
#pragma unroll
      for (int nf = 0; nf < 4; ++nf)
        acc[mf][nf] = __builtin_amdgcn_mfma_f32_16x16x32_bf16(
            af[mf], bq[nf], acc[mf][nf], 0, 0, 0);
    __builtin_amdgcn_s_setprio(0);
    __asm__ volatile("s_waitcnt vmcnt(0)" ::: "memory");   // t+1 landed
    __builtin_amdgcn_s_barrier();
    __asm__ volatile("" ::: "memory");
  }

  // ---- hoist capsule weights/bias into regs, then reuse LDS ----
  int gb = nb * 8 + (wv & 1) * 4;   // wave's 4 consecutive global groups
  s16x8 wf[4];
  f32x4 cinit[4];
#pragma unroll
  for (int g = 0; g < 4; ++g) {
    int gg = gb + g;
    s16x8 bw = {0, 0, 0, 0, 0, 0, 0, 0};
    if (lq < 2) {
#pragma unroll
      for (int j = 0; j < 8; ++j)
        bw[j] = (short)bfbits(capsW[(8 * lq + j) * 512 + gg * 16 + col]);
    }
    wf[g] = bw;
    float cb = capsB[gg * 16 + col];
    cinit[g] = f32x4{cb, cb, cb, cb};
  }
  float b1v[4];
  int nBase = nb * 128 + wn;
#pragma unroll
  for (int nf = 0; nf < 4; ++nf) b1v[nf] = bias1[nBase + nf * 16 + col];

  __asm__ volatile("s_waitcnt vmcnt(0) lgkmcnt(0)" ::: "memory");
  __builtin_amdgcn_s_barrier();
  __asm__ volatile("" ::: "memory");

  // ---- epilogue: y = relu(acc + bias1) -> per-wave swizzled LDS (bf16) ----
  __hip_bfloat16* yw = smem_e + wv * 4096;   // 64px x 64n per wave (4 x 8KB = 32KB)
#pragma unroll
  for (int nf = 0; nf < 4; ++nf) {
#pragma unroll
    for (int mf = 0; mf < 4; ++mf) {
      f32x4 a = acc[mf][nf];
#pragma unroll
      for (int r = 0; r < 4; ++r) {
        int pl = mf * 16 + lq * 4 + r;
        int nl = nf * 16 + col;
        float v = a[r] + b1v[nf];
        v = v > 0.f ? v : 0.f;
        int off = (pl * 128 + nl * 2) ^ ((pl & 7) << 4);
        *(unsigned short*)((char*)yw + off) = bfbits(v);
      }
    }
  }
  __asm__ volatile("s_waitcnt lgkmcnt(0)" ::: "memory");

  // ---- capsule 16x16 matmul per group via MFMA (K=16 zero-padded) ----
#pragma unroll
  for (int mf = 0; mf < 4; ++mf) {
    int prow = 16 * mf + col;
    f32x4 dd[4];
#pragma unroll
    for (int g = 0; g < 4; ++g) {
      s16x8 afv = {0, 0, 0, 0, 0, 0, 0, 0};
      if (lq < 2) {
        int off = (prow * 128 + g * 32 + lq * 16) ^ ((prow & 7) << 4);
        afv = *(const s16x8*)((char*)yw + off);
      }
      dd[g] = __builtin_amdgcn_mfma_f32_16x16x32_bf16(afv, wf[g], cinit[g], 0, 0, 0);
    }
    long pgl = (long)(p0 + wm) + 16 * mf;
#pragma unroll
    for (int r = 0; r < 4; ++r) {
      long pg = pgl + 4 * lq + r;
      f32x4 o = {dd[0][r], dd[1][r], dd[2][r], dd[3][r]};
      *(f32x4*)(out + (pg * 16 + col) * 32 + gb) = o;
    }
  }
}

// ---------------------------------------------------------------------------
// Fallback (round-1 kernel, needs only 2.4 MB ws) in case ws is small
// ---------------------------------------------------------------------------
__global__ __launch_bounds__(256, 3)
void caps_main_v1(const float* __restrict__ in, const __hip_bfloat16* __restrict__ wt,
                  const float* __restrict__ bias1, const float* __restrict__ capsW,
                  const float* __restrict__ capsB, float* __restrict__ out) {
  __shared__ __align__(16) unsigned char smem[32768];
  __hip_bfloat16* sA = (__hip_bfloat16*)smem;
  __hip_bfloat16* sB = (__hip_bfloat16*)(smem + 8192);

  int bid = (int)blockIdx.x;
  bid = (bid & 7) * 98 + (bid >> 3);
  int mblk = bid >> 2;
  int nb = bid & 3;
  int p0 = mblk * 128;

  int tid = threadIdx.x;
  int lane = tid & 63;
  int wv = tid >> 6;
  int wm = (wv >> 1) * 64;
  int wn = (wv & 1) * 64;
  int col = lane & 15;
  int lq = lane >> 4;

  int am = tid & 127;
  int ah = tid >> 7;
  int p = p0 + am;
  int bb = p / 784;
  int rr = p - bb * 784;
  int ho = rr / 28;
  int wo = rr - ho * 28;

  f32x4 acc[4][4] = {};
  const __hip_bfloat16* wtb = wt + nb * 4096;

  for (int kp = 0; kp < 9; ++kp) {
    int kh = kp / 3;
    int kw = kp - kh * 3;
    int h = 2 * ho + kh, ww = 2 * wo + kw;
    bool valid = (h < 56) && (ww < 56);
    const float* arow = in + (((bb * 56 + h) * 56 + ww) * 256) + ah * 16;
#pragma unroll
    for (int tc = 0; tc < 8; ++tc) {
      int t = kp * 8 + tc;
      __syncthreads();
      const __hip_bfloat16* bsrc = wtb + t * 16384 + tid * 8;
      gll16(sB + (wv * 512), bsrc);
      gll16(sB + 2048 + (wv * 512), bsrc + 2048);
      f32x4 v0, v1, v2, v3;
      if (valid) {
        const f32x4* apv = (const f32x4*)(arow + tc * 32);
        v0 = apv[0]; v1 = apv[1]; v2 = apv[2]; v3 = apv[3];
      } else {
        v0 = f32x4{0.f, 0.f, 0.f, 0.f}; v1 = v0; v2 = v0; v3 = v0;
      }
      u16x8 pk0, pk1;
#pragma unroll
      for (int j = 0; j < 4; ++j) {
        pk0[j] = bfbits(v0[j]); pk0[j + 4] = bfbits(v1[j]);
        pk1[j] = bfbits(v2[j]); pk1[j + 4] = bfbits(v3[j]);
      }
      *(u16x8*)(sA + (ah * 2) * 1024 + am * 8) = pk0;
      *(u16x8*)(sA + (ah * 2 + 1) * 1024 + am * 8) = pk1;
      __syncthreads();
      s16x8 af[4], bfr[4];
#pragma unroll
      for (int mf = 0; mf < 4; ++mf)
        af[mf] = *(const s16x8*)(sA + lq * 1024 + (wm + 16 * mf + col) * 8);
#pragma unroll
      for (int nf = 0; nf < 4; ++nf)
        bfr[nf] = *(const s16x8*)(sB + lq * 1024 + (wn + 16 * nf + col) * 8);
#pragma unroll
      for (int mf = 0; mf < 4; ++mf)
#pragma unroll
        for (int nf = 0; nf < 4; ++nf)
          acc[mf][nf] = __builtin_amdgcn_mfma_f32_16x16x32_bf16(
              af[mf], bfr[nf], acc[mf][nf], 0, 0, 0);
    }
  }

  __syncthreads();

  __hip_bfloat16* yw = (__hip_bfloat16*)smem + wv * 4096;
  int nBase = nb * 128 + wn;
#pragma unroll
  for (int nf = 0; nf < 4; ++nf) {
    float b1v = bias1[nBase + nf * 16 + col];
#pragma unroll
    for (int mf = 0; mf < 4; ++mf) {
      f32x4 a = acc[mf][nf];
#pragma unroll
      for (int r = 0; r < 4; ++r) {
        int pl = mf * 16 + lq * 4 + r;
        int nl = nf * 16 + col;
        float v = a[r] + b1v;
        v = v > 0.f ? v : 0.f;
        int off = (pl * 128 + nl * 2) ^ ((pl & 7) << 4);
        *(unsigned short*)((char*)yw + off) = bfbits(v);
      }
    }
  }

  int gb = nb * 8 + (wv & 1) * 4;
  s16x8 wf[4];
  f32x4 cinit[4];
#pragma unroll
  for (int g = 0; g < 4; ++g) {
    int gg = gb + g;
    s16x8 bw = {0, 0, 0, 0, 0, 0, 0, 0};
    if (lq < 2) {
#pragma unroll
      for (int j = 0; j < 8; ++j)
        bw[j] = (short)bfbits(capsW[(8 * lq + j) * 512 + gg * 16 + col]);
    }
    wf[g] = bw;
    float cb = capsB[gg * 16 + col];
    cinit[g] = f32x4{cb, cb, cb, cb};
  }
#pragma unroll
  for (int mf = 0; mf < 4; ++mf) {
    int prow = 16 * mf + col;
    f32x4 dd[4];
#pragma unroll
    for (int g = 0; g < 4; ++g) {
      s16x8 afv = {0, 0, 0, 0, 0, 0, 0, 0};
      if (lq < 2) {
        int off = (prow * 128 + g * 32 + lq * 16) ^ ((prow & 7) << 4);
        afv = *(const s16x8*)((char*)yw + off);
      }
      dd[g] = __builtin_amdgcn_mfma_f32_16x16x32_bf16(afv, wf[g], cinit[g], 0, 0, 0);
    }
    long pgl = (long)(p0 + wm) + 16 * mf;
#pragma unroll
    for (int r = 0; r < 4; ++r) {
      long pg = pgl + 4 * lq + r;
      f32x4 o = {dd[0][r], dd[1][r], dd[2][r], dd[3][r]};
      *(f32x4*)(out + (pg * 16 + col) * 32 + gb) = o;
    }
  }
}

extern "C" void kernel_launch(void* const* d_in, const int* in_sizes, int n_in,
                              void* d_out, int out_size, void* d_ws, size_t ws_size,
                              hipStream_t stream) {
  const float* inputs = (const float*)d_in[0];
  const float* convW  = (const float*)d_in[1];
  const float* bias1  = (const float*)d_in[2];
  const float* capsW  = (const float*)d_in[3];
  const float* capsB  = (const float*)d_in[4];
  float* out = (float*)d_out;

  __hip_bfloat16* wt = (__hip_bfloat16*)d_ws;                 // 2.36 MB
  const size_t IN_OFF = 2621440;                              // 2.5 MB
  const size_t NEED = IN_OFF + (size_t)27082752 * 2;          // 56.8 MB

  if (ws_size >= NEED) {
    __hip_bfloat16* inp = (__hip_bfloat16*)((char*)d_ws + IN_OFF);
    prep_all<<<2400, 256, 0, stream>>>(inputs, inp, convW, wt);
    caps_main_fast<<<784, 256, 0, stream>>>(inp, wt, bias1, capsW, capsB, out);
  } else {
    prep_all<<<2400, 256, 0, stream>>>(inputs, (__hip_bfloat16*)d_ws, convW, wt); // wt part only valid
    caps_main_v1<<<784, 256, 0, stream>>>(inputs, wt, bias1, capsW, capsB, out);
  }
}

// Round 12
// 98.953 us; speedup vs baseline: 2.7679x; 2.7679x over previous
//
#include <hip/hip_runtime.h>
#include <hip/hip_bf16.h>

typedef __attribute__((ext_vector_type(4))) float f32x4;
typedef __attribute__((ext_vector_type(8))) short s16x8;
typedef __attribute__((ext_vector_type(8))) unsigned short u16x8;
typedef __attribute__((ext_vector_type(4))) unsigned short u16x4;

__device__ __forceinline__ unsigned short bfbits(float f) {
  unsigned int u = __builtin_bit_cast(unsigned int, f);
  return (unsigned short)((u + 0x8000u) >> 16);   // round-half-up to bf16
}

__device__ __forceinline__ void gll16(void* lds, const void* g) {
  __builtin_amdgcn_global_load_lds(
      (const __attribute__((address_space(1))) unsigned int*)g,
      (__attribute__((address_space(3))) unsigned int*)lds, 16, 0, 0);
}

// ---------------------------------------------------------------------------
// Merged prep: blocks [0,1824) transpose input, blocks [1824,2400) tile weights.
// Input: [32,56,56,256] f32 -> bf16 [b][h57][par][cq32][wp29][8]
//   element strides: wp:8 cq:232 par:7424 h:14848 b:846336
// Weights: [3,3,256,512] f32 -> bf16, K-step t=kpos*8+c/32, nb: [cq][nl][ce]
//   Wt index = (t*4+nb)*4096 + cq*1024 + nl*8 + ce
// ---------------------------------------------------------------------------
__global__ __launch_bounds__(256)
void prep_all(const float* __restrict__ in, __hip_bfloat16* __restrict__ dst,
              const float* __restrict__ w, __hip_bfloat16* __restrict__ wt) {
  int t = threadIdx.x;
  if (blockIdx.x < 1824) {
    __shared__ __align__(16) unsigned short row[14848];
    int bh = blockIdx.x;            // 32*57
    int h = bh % 57, b = bh / 57;
    __hip_bfloat16* d = (__hip_bfloat16*)dst + (long)bh * 14848;
    if (h < 56) {
      if (t < 64) {   // zero the wp=28 pad slots
        int par = t >> 5, cq = t & 31;
        u16x4 z = {0, 0, 0, 0};
        *(u16x4*)(row + (par * 32 + cq) * 232 + 224) = z;
        *(u16x4*)(row + (par * 32 + cq) * 232 + 228) = z;
      }
      const float* src = in + (long)(b * 56 + h) * 56 * 256;
#pragma unroll
      for (int j = 0; j < 14; ++j) {
        int idx = j * 256 + t;       // f32x4 index in row, 3584 total
        f32x4 v = *(const f32x4*)(src + idx * 4);
        int e0 = idx * 4;
        int ww = e0 >> 8, c = e0 & 255;
        int off = ((ww & 1) * 32 + (c >> 3)) * 232 + (ww >> 1) * 8 + (c & 7);
        u16x4 q = {bfbits(v[0]), bfbits(v[1]), bfbits(v[2]), bfbits(v[3])};
        *(u16x4*)(row + off) = q;
      }
      __syncthreads();
      for (int i = t; i < 1856; i += 256)
        *(u16x8*)(d + i * 8) = *(const u16x8*)(row + i * 8);
    } else {
      u16x8 z = {0, 0, 0, 0, 0, 0, 0, 0};
      for (int i = t; i < 1856; i += 256) *(u16x8*)(d + i * 8) = z;
    }
  } else {
    int u = (blockIdx.x - 1824) * 256 + t;   // 147456 threads
    int n = u & 511;
    int c8 = (u >> 9) & 31;
    int kpos = u >> 14;
    int tt = kpos * 8 + (c8 >> 2);
    int cq = c8 & 3;
    const float* src = w + ((kpos * 256 + c8 * 8) * 512) + n;
    u16x8 d;
#pragma unroll
    for (int j = 0; j < 8; ++j) d[j] = bfbits(src[j * 512]);
    int nb = n >> 7, nl = n & 127;
    *reinterpret_cast<u16x8*>(wt + ((tt * 4 + nb) * 4096 + cq * 1024 + nl * 8)) = d;
  }
}

// ---------------------------------------------------------------------------
// Main: implicit-GEMM conv, BM=256 BN=128 BK=32, 256 threads = 4 FAT waves,
// each owning a 128x64 output tile (acc[8][4], HK-style). Registers capped
// at 256/wave via launch_bounds(256,2) -> spill-free by construction.
// R8 chassis: 3 LDS bufs x (A16K+B8K)=72KB, depth-2 prefetch, counted
// vmcnt(6), one raw barrier per K-step. Per-CU LDS frag traffic -25% vs R8;
// per-wave MFMA cluster 4x bigger (32) for in-wave latency hiding.
// ---------------------------------------------------------------------------
__global__ __launch_bounds__(256, 2)
void caps_main_fast(const __hip_bfloat16* __restrict__ inp,   // transposed bf16
                    const __hip_bfloat16* __restrict__ wt,
                    const float* __restrict__ bias1,
                    const float* __restrict__ capsW,
                    const float* __restrict__ capsB,
                    float* __restrict__ out) {
  __shared__ __align__(16) unsigned char smem[73728];   // 3 x (A 16KB + B 8KB)
  __hip_bfloat16* smem_e = (__hip_bfloat16*)smem;

  int bid = (int)blockIdx.x;
  bid = (bid & 7) * 49 + (bid >> 3);   // XCD swizzle (392 = 8*49)
  int mblk = bid >> 2;                 // 0..97
  int nb = bid & 3;
  int p0 = mblk * 256;

  int tid = threadIdx.x;
  int lane = tid & 63;
  int wv = tid >> 6;                   // 0..3
  int wm2 = (wv >> 1) * 128;           // wave m offset (128-row tile)
  int wn = (wv & 1) * 64;              // wave n offset
  int col = lane & 15;
  int lq = lane >> 4;

  // A staging: wave wv stages cq=wv; lanes = pixels; 4 px-blocks of 64
  int baseA[4];
#pragma unroll
  for (int pb = 0; pb < 4; ++pb) {
    int p = p0 + pb * 64 + lane;
    int b = p / 784;
    int rr = p - b * 784;
    int ho = rr / 28;
    int wo = rr - ho * 28;
    baseA[pb] = b * 846336 + 2 * ho * 14848 + wo * 8;
  }

  const __hip_bfloat16* wtb = wt + nb * 4096;

  f32x4 acc[8][4] = {};

  auto stage = [&](int buf, int t) {
    int kp = t >> 3, tc = t & 7;
    int kh = (kp * 11) >> 5;           // kp/3 for kp in 0..8
    int kw = kp - kh * 3;
    int koff = kh * 14848 + (kw & 1) * 7424 + (kw >> 1) * 8 + (tc * 4 + wv) * 232;
    __hip_bfloat16* sa = smem_e + buf * 12288;
    // A tile [cq4][256px][8]: wave wv covers cq=wv (4 gll, 16B/lane coalesced)
#pragma unroll
    for (int pb = 0; pb < 4; ++pb)
      gll16(sa + wv * 2048 + pb * 512, inp + baseA[pb] + koff);
    // B tile [cq4][128nl][8]: wave wv covers cq=wv (2 gll)
    __hip_bfloat16* sb = sa + 8192;
    const __hip_bfloat16* bs = wtb + t * 16384 + wv * 1024 + lane * 8;
    gll16(sb + wv * 1024, bs);
    gll16(sb + wv * 1024 + 512, bs + 512);
  };

  // prologue: tiles 0,1 staged (12 loads); tile 0 landed; tile 1 in flight
  stage(0, 0);
  stage(1, 1);
  __asm__ volatile("s_waitcnt vmcnt(6)" ::: "memory");
  __builtin_amdgcn_s_barrier();
  __asm__ volatile("" ::: "memory");

  int rd = 0;
  for (int t = 0; t < 72; ++t) {
    const __hip_bfloat16* sa = smem_e + rd * 12288;
    const __hip_bfloat16* sb = sa + 8192;
    s16x8 af[8], bq[4];
#pragma unroll
    for (int mf = 0; mf < 8; ++mf)
      af[mf] = *(const s16x8*)(sa + lq * 2048 + (wm2 + 16 * mf + col) * 8);
#pragma unroll
    for (int nf = 0; nf < 4; ++nf)
      bq[nf] = *(const s16x8*)(sb + lq * 1024 + (wn + 16 * nf + col) * 8);
    if (t + 2 < 72) {
      int st = rd + 2; if (st >= 3) st -= 3;
      stage(st, t + 2);
    }
    __builtin_amdgcn_s_setprio(1);
#pragma unroll
    for (int mf = 0; mf < 8; ++mf)
#pragma unroll
      for (int nf = 0; nf < 4; ++nf)
        acc[mf][nf] = __builtin_amdgcn_mfma_f32_16x16x32_bf16(
            af[mf], bq[nf], acc[mf][nf], 0, 0, 0);
    __builtin_amdgcn_s_setprio(0);
    if (t < 70) {
      __asm__ volatile("s_waitcnt vmcnt(6)" ::: "memory");   // t+1 landed
    } else if (t == 70) {
      __asm__ volatile("s_waitcnt vmcnt(0)" ::: "memory");
    }
    __builtin_amdgcn_s_barrier();
    __asm__ volatile("" ::: "memory");
    rd = (rd + 1 == 3) ? 0 : rd + 1;
  }

  // ---- hoist capsule weights/bias into regs, then reuse LDS ----
  int gb = nb * 8 + (wv & 1) * 4;   // wave's 4 consecutive global groups
  s16x8 wf[4];
  f32x4 cinit[4];
#pragma unroll
  for (int g = 0; g < 4; ++g) {
    int gg = gb + g;
    s16x8 bw = {0, 0, 0, 0, 0, 0, 0, 0};
    if (lq < 2) {
#pragma unroll
      for (int j = 0; j < 8; ++j)
        bw[j] = (short)bfbits(capsW[(8 * lq + j) * 512 + gg * 16 + col]);
    }
    wf[g] = bw;
    float cb = capsB[gg * 16 + col];
    cinit[g] = f32x4{cb, cb, cb, cb};
  }
  float b1v[4];
  int nBase = nb * 128 + wn;
#pragma unroll
  for (int nf = 0; nf < 4; ++nf) b1v[nf] = bias1[nBase + nf * 16 + col];

  __asm__ volatile("s_waitcnt vmcnt(0) lgkmcnt(0)" ::: "memory");
  __builtin_amdgcn_s_barrier();
  __asm__ volatile("" ::: "memory");

  // ---- epilogue: y = relu(acc + bias1) -> per-wave swizzled LDS (bf16) ----
  // wave region: 128px x 64n = 16KB; 4 waves = 64KB <= 72KB
  __hip_bfloat16* yw = smem_e + wv * 8192;
#pragma unroll
  for (int nf = 0; nf < 4; ++nf) {
#pragma unroll
    for (int mf = 0; mf < 8; ++mf) {
      f32x4 a = acc[mf][nf];
#pragma unroll
      for (int r = 0; r < 4; ++r) {
        int pl = mf * 16 + lq * 4 + r;          // 0..127
        int nl = nf * 16 + col;
        float v = a[r] + b1v[nf];
        v = v > 0.f ? v : 0.f;
        int off = (pl * 128 + nl * 2) ^ ((pl & 7) << 4);
        *(unsigned short*)((char*)yw + off) = bfbits(v);
      }
    }
  }
  __asm__ volatile("s_waitcnt lgkmcnt(0)" ::: "memory");

  // ---- capsule 16x16 matmul per group via MFMA (K=16 zero-padded) ----
#pragma unroll
  for (int mf = 0; mf < 8; ++mf) {
    int prow = 16 * mf + col;                   // 0..127
    f32x4 dd[4];
#pragma unroll
    for (int g = 0; g < 4; ++g) {
      s16x8 afv = {0, 0, 0, 0, 0, 0, 0, 0};
      if (lq < 2) {
        int off = (prow * 128 + g * 32 + lq * 16) ^ ((prow & 7) << 4);
        afv = *(const s16x8*)((char*)yw + off);
      }
      dd[g] = __builtin_amdgcn_mfma_f32_16x16x32_bf16(afv, wf[g], cinit[g], 0, 0, 0);
    }
    long pgl = (long)(p0 + wm2) + 16 * mf;
#pragma unroll
    for (int r = 0; r < 4; ++r) {
      long pg = pgl + 4 * lq + r;
      f32x4 o = {dd[0][r], dd[1][r], dd[2][r], dd[3][r]};
      *(f32x4*)(out + (pg * 16 + col) * 32 + gb) = o;
    }
  }
}

// ---------------------------------------------------------------------------
// Fallback (round-1 kernel, needs only 2.4 MB ws) in case ws is small
// ---------------------------------------------------------------------------
__global__ __launch_bounds__(256, 3)
void caps_main_v1(const float* __restrict__ in, const __hip_bfloat16* __restrict__ wt,
                  const float* __restrict__ bias1, const float* __restrict__ capsW,
                  const float* __restrict__ capsB, float* __restrict__ out) {
  __shared__ __align__(16) unsigned char smem[32768];
  __hip_bfloat16* sA = (__hip_bfloat16*)smem;
  __hip_bfloat16* sB = (__hip_bfloat16*)(smem + 8192);

  int bid = (int)blockIdx.x;
  bid = (bid & 7) * 98 + (bid >> 3);
  int mblk = bid >> 2;
  int nb = bid & 3;
  int p0 = mblk * 128;

  int tid = threadIdx.x;
  int lane = tid & 63;
  int wv = tid >> 6;
  int wm = (wv >> 1) * 64;
  int wn = (wv & 1) * 64;
  int col = lane & 15;
  int lq = lane >> 4;

  int am = tid & 127;
  int ah = tid >> 7;
  int p = p0 + am;
  int bb = p / 784;
  int rr = p - bb * 784;
  int ho = rr / 28;
  int wo = rr - ho * 28;

  f32x4 acc[4][4] = {};
  const __hip_bfloat16* wtb = wt + nb * 4096;

  for (int kp = 0; kp < 9; ++kp) {
    int kh = kp / 3;
    int kw = kp - kh * 3;
    int h = 2 * ho + kh, ww = 2 * wo + kw;
    bool valid = (h < 56) && (ww < 56);
    const float* arow = in + (((bb * 56 + h) * 56 + ww) * 256) + ah * 16;
#pragma unroll
    for (int tc = 0; tc < 8; ++tc) {
      int t = kp * 8 + tc;
      __syncthreads();
      const __hip_bfloat16* bsrc = wtb + t * 16384 + tid * 8;
      gll16(sB + (wv * 512), bsrc);
      gll16(sB + 2048 + (wv * 512), bsrc + 2048);
      f32x4 v0, v1, v2, v3;
      if (valid) {
        const f32x4* apv = (const f32x4*)(arow + tc * 32);
        v0 = apv[0]; v1 = apv[1]; v2 = apv[2]; v3 = apv[3];
      } else {
        v0 = f32x4{0.f, 0.f, 0.f, 0.f}; v1 = v0; v2 = v0; v3 = v0;
      }
      u16x8 pk0, pk1;
#pragma unroll
      for (int j = 0; j < 4; ++j) {
        pk0[j] = bfbits(v0[j]); pk0[j + 4] = bfbits(v1[j]);
        pk1[j] = bfbits(v2[j]); pk1[j + 4] = bfbits(v3[j]);
      }
      *(u16x8*)(sA + (ah * 2) * 1024 + am * 8) = pk0;
      *(u16x8*)(sA + (ah * 2 + 1) * 1024 + am * 8) = pk1;
      __syncthreads();
      s16x8 af[4], bfr[4];
#pragma unroll
      for (int mf = 0; mf < 4; ++mf)
        af[mf] = *(const s16x8*)(sA + lq * 1024 + (wm + 16 * mf + col) * 8);
#pragma unroll
      for (int nf = 0; nf < 4; ++nf)
        bfr[nf] = *(const s16x8*)(sB + lq * 1024 + (wn + 16 * nf + col) * 8);
#pragma unroll
      for (int mf = 0; mf < 4; ++mf)
#pragma unroll
        for (int nf = 0; nf < 4; ++nf)
          acc[mf][nf] = __builtin_amdgcn_mfma_f32_16x16x32_bf16(
              af[mf], bfr[nf], acc[mf][nf], 0, 0, 0);
    }
  }

  __syncthreads();

  __hip_bfloat16* yw = (__hip_bfloat16*)smem + wv * 4096;
  int nBase = nb * 128 + wn;
#pragma unroll
  for (int nf = 0; nf < 4; ++nf) {
    float b1v = bias1[nBase + nf * 16 + col];
#pragma unroll
    for (int mf = 0; mf < 4; ++mf) {
      f32x4 a = acc[mf][nf];
#pragma unroll
      for (int r = 0; r < 4; ++r) {
        int pl = mf * 16 + lq * 4 + r;
        int nl = nf * 16 + col;
        float v = a[r] + b1v;
        v = v > 0.f ? v : 0.f;
        int off = (pl * 128 + nl * 2) ^ ((pl & 7) << 4);
        *(unsigned short*)((char*)yw + off) = bfbits(v);
      }
    }
  }

  int gb = nb * 8 + (wv & 1) * 4;
  s16x8 wf[4];
  f32x4 cinit[4];
#pragma unroll
  for (int g = 0; g < 4; ++g) {
    int gg = gb + g;
    s16x8 bw = {0, 0, 0, 0, 0, 0, 0, 0};
    if (lq < 2) {
#pragma unroll
      for (int j = 0; j < 8; ++j)
        bw[j] = (short)bfbits(capsW[(8 * lq + j) * 512 + gg * 16 + col]);
    }
    wf[g] = bw;
    float cb = capsB[gg * 16 + col];
    cinit[g] = f32x4{cb, cb, cb, cb};
  }
#pragma unroll
  for (int mf = 0; mf < 4; ++mf) {
    int prow = 16 * mf + col;
    f32x4 dd[4];
#pragma unroll
    for (int g = 0; g < 4; ++g) {
      s16x8 afv = {0, 0, 0, 0, 0, 0, 0, 0};
      if (lq < 2) {
        int off = (prow * 128 + g * 32 + lq * 16) ^ ((prow & 7) << 4);
        afv = *(const s16x8*)((char*)yw + off);
      }
      dd[g] = __builtin_amdgcn_mfma_f32_16x16x32_bf16(afv, wf[g], cinit[g], 0, 0, 0);
    }
    long pgl = (long)(p0 + wm) + 16 * mf;
#pragma unroll
    for (int r = 0; r < 4; ++r) {
      long pg = pgl + 4 * lq + r;
      f32x4 o = {dd[0][r], dd[1][r], dd[2][r], dd[3][r]};
      *(f32x4*)(out + (pg * 16 + col) * 32 + gb) = o;
    }
  }
}

extern "C" void kernel_launch(void* const* d_in, const int* in_sizes, int n_in,
                              void* d_out, int out_size, void* d_ws, size_t ws_size,
                              hipStream_t stream) {
  const float* inputs = (const float*)d_in[0];
  const float* convW  = (const float*)d_in[1];
  const float* bias1  = (const float*)d_in[2];
  const float* capsW  = (const float*)d_in[3];
  const float* capsB  = (const float*)d_in[4];
  float* out = (float*)d_out;

  __hip_bfloat16* wt = (__hip_bfloat16*)d_ws;                 // 2.36 MB
  const size_t IN_OFF = 2621440;                              // 2.5 MB
  const size_t NEED = IN_OFF + (size_t)27082752 * 2;          // 56.8 MB

  if (ws_size >= NEED) {
    __hip_bfloat16* inp = (__hip_bfloat16*)((char*)d_ws + IN_OFF);
    prep_all<<<2400, 256, 0, stream>>>(inputs, inp, convW, wt);
    caps_main_fast<<<392, 256, 0, stream>>>(inp, wt, bias1, capsW, capsB, out);
  } else {
    prep_all<<<2400, 256, 0, stream>>>(inputs, (__hip_bfloat16*)d_ws, convW, wt); // wt part only valid
    caps_main_v1<<<784, 256, 0, stream>>>(inputs, wt, bias1, capsW, capsB, out);
  }
}